// Round 3
// baseline (390.987 us; speedup 1.0000x reference)
//
#include <hip/hip_runtime.h>
#include <stdint.h>

// BinaryDense: out[8192,4096] = x[8192,4096] @ sign(kernel[4096,4096]) + bias[4096]
// R6: 32x32x32 i8 MFMA + ping-ponged operand sets. R5's limit: next-phase ds_reads
// targeted the SAME a/b regs the current MFMAs read (WAR) -> reads could only issue
// after the last MFMA -> LDS service (~512c) serial with MFMA (~653c) = 1344c/phase.
// 32x32x32 (4404 TOPS vs 3944; 36.6 cyc/SIMD per instr) needs only a[4]+b[2] per
// kk-step -> TWO sets fit: acc 128 + 2x24 operand + addr < 256 regs @ 2 waves/SIMD.
// Tile loop (BM=BN=256, BK=128, 2 bufs of 64KB, 8 waves of 128x64):
//   tile t (buf P): s1{rd(s2)->Y; stage(t+1->~P); mfma s1 X}
//                   s2{rd(s3)->X; mfma s2 Y}  s3{rd(s4)->Y; mfma s3 X}
//                   vmcnt(0) [stage issued ~1750c ago, L2 lat ~200-400 -> drained]
//                   barrier; s4{rd(t+1,s1)->X; mfma s4 Y}; barrier.
// Safety: stage(t+1->~P) at t.s1 is 1 barrier after ~P's last reads (consumed
// before t-1.s4's MFMA, which precedes the tile-end barrier). reads(t+1) follow
// the mid-tile vmcnt+barrier. Reads always overlap MFMA via the free set.
// LDS: row r (128B) chunk q at slot q^(r&7); gload_lds dest linear, global source
// carries the inverse permutation (rule 21). 32-lane x b128 access covers all 32
// banks per 8 rows -> conflict-free.

typedef int int4v __attribute__((ext_vector_type(4)));
typedef int int16v __attribute__((ext_vector_type(16)));

constexpr int M = 8192, N = 4096, K = 4096;
constexpr int BM = 256, BN = 256, BK = 128;  // i8 elements (= bytes)
constexpr int NT = K / BK;                   // 32 K-tiles

__device__ __forceinline__ void gload_lds16(const void* g, void* l) {
  __builtin_amdgcn_global_load_lds(
      (const __attribute__((address_space(1))) unsigned int*)g,
      (__attribute__((address_space(3))) unsigned int*)l, 16, 0, 0);
}

#define FENCE asm volatile("" ::: "memory")

// ---- kernel 1: fused prep. blocks [0,M): per-row absmax quantize x -> i8.
//      blocks [M, M+N/64*K/64): sign(w)^T 64x64 tiles. Overlaps both BW streams.
__global__ __launch_bounds__(256) void prep_kernel(const float* __restrict__ x,
                                                   signed char* __restrict__ xq,
                                                   float* __restrict__ rscale,
                                                   const float* __restrict__ w,
                                                   signed char* __restrict__ wq) {
  const int t = threadIdx.x;
  if (blockIdx.x < M) {
    const int row = blockIdx.x;
    const float* xr = x + (size_t)row * K;
    float4 v[4];
    float mx = 0.f;
#pragma unroll
    for (int i = 0; i < 4; ++i) {
      v[i] = *(const float4*)(xr + t * 16 + i * 4);
      mx = fmaxf(mx, fmaxf(fmaxf(fabsf(v[i].x), fabsf(v[i].y)),
                           fmaxf(fabsf(v[i].z), fabsf(v[i].w))));
    }
#pragma unroll
    for (int off = 32; off >= 1; off >>= 1)
      mx = fmaxf(mx, __shfl_xor(mx, off, 64));
    __shared__ float smax[4];
    if ((t & 63) == 0) smax[t >> 6] = mx;
    __syncthreads();
    const float rm = fmaxf(fmaxf(smax[0], smax[1]), fmaxf(smax[2], smax[3]));
    const float s = (rm > 0.f) ? 127.f / rm : 0.f;
    if (t == 0) rscale[row] = (rm > 0.f) ? rm / 127.f : 0.f;
    uint32_t o[4];
#pragma unroll
    for (int i = 0; i < 4; ++i) {
      float f[4] = {v[i].x, v[i].y, v[i].z, v[i].w};
      uint32_t p = 0;
#pragma unroll
      for (int j = 0; j < 4; ++j) {
        int q = (int)rintf(f[j] * s);  // in [-127,127] by construction
        p |= ((uint32_t)(uint8_t)(signed char)q) << (8 * j);
      }
      o[i] = p;
    }
    *(int4v*)(xq + (size_t)row * K + t * 16) =
        (int4v){(int)o[0], (int)o[1], (int)o[2], (int)o[3]};
  } else {
    __shared__ __align__(16) signed char tile[64 * 68];  // pad 68
    const int idx = blockIdx.x - M;
    const int n0 = (idx & 63) * 64, k0 = (idx >> 6) * 64;
#pragma unroll
    for (int i = 0; i < 4; ++i) {
      int kl = (t >> 4) + i * 16;  // 0..63
      int nl = (t & 15) * 4;       // 0..60
      float4 v = *(const float4*)(w + (size_t)(k0 + kl) * N + n0 + nl);
      uint32_t p = 0;
      p |= ((uint32_t)(uint8_t)(signed char)((v.x > 0.f) - (v.x < 0.f)));
      p |= ((uint32_t)(uint8_t)(signed char)((v.y > 0.f) - (v.y < 0.f))) << 8;
      p |= ((uint32_t)(uint8_t)(signed char)((v.z > 0.f) - (v.z < 0.f))) << 16;
      p |= ((uint32_t)(uint8_t)(signed char)((v.w > 0.f) - (v.w < 0.f))) << 24;
      *(uint32_t*)(tile + kl * 68 + nl) = p;
    }
    __syncthreads();
    const int nl = t >> 2;        // 0..63
    const int kc = (t & 3) * 16;  // 0,16,32,48
    uint32_t o[4] = {0, 0, 0, 0};
#pragma unroll
    for (int j = 0; j < 16; ++j)
      o[j >> 2] |= ((uint32_t)(uint8_t)tile[(kc + j) * 68 + nl]) << (8 * (j & 3));
    *(int4v*)(wq + (size_t)(n0 + nl) * K + k0 + kc) =
        (int4v){(int)o[0], (int)o[1], (int)o[2], (int)o[3]};
  }
}

// ---- kernel 2: i8 32x32x32 MFMA GEMM, ping-pong operand pipeline ----
// A = Xq [M][K] i8, B = Wq [N][K] i8, acc int32 (exact), dequant in epilogue.
// A-frag: row=lane&31, k=(lane>>5)*16+byte (chunk = kk*2+hi). B symmetric.

#define RD_SET(AN, BN_, P, KK)                                                    \
  {                                                                               \
    _Pragma("unroll") for (int mi_ = 0; mi_ < 4; ++mi_) {                         \
      const int r_ = wm * 128 + mi_ * 32 + l31;                                   \
      AN[mi_] = *(const int4v*)(smem + (P)*65536 + r_ * 128 +                     \
                                ((((KK)*2 + hi) ^ (r_ & 7)) * 16));               \
    }                                                                             \
    _Pragma("unroll") for (int ni_ = 0; ni_ < 2; ++ni_) {                         \
      const int r_ = wn * 64 + ni_ * 32 + l31;                                    \
      BN_[ni_] = *(const int4v*)(smem + (P)*65536 + 32768 + r_ * 128 +            \
                                 ((((KK)*2 + hi) ^ (r_ & 7)) * 16));              \
    }                                                                             \
  }

#define MM(AN, BN_)                                                               \
  {                                                                               \
    __builtin_amdgcn_s_setprio(1);                                                \
    _Pragma("unroll") for (int mi_ = 0; mi_ < 4; ++mi_) {                         \
      _Pragma("unroll") for (int ni_ = 0; ni_ < 2; ++ni_) {                       \
        acc[mi_][ni_] = __builtin_amdgcn_mfma_i32_32x32x32_i8(                    \
            AN[mi_], BN_[ni_], acc[mi_][ni_], 0, 0, 0);                           \
      }                                                                           \
    }                                                                             \
    __builtin_amdgcn_s_setprio(0);                                                \
  }

// tile with parity P (reads buf P; stages tile TS into buf NP when MORE)
#define TILE(P, NP, TS, MORE)                                                     \
  {                                                                               \
    RD_SET(aY, bY, P, 1);                                                         \
    if (MORE) stage(NP, TS);                                                      \
    MM(aX, bX); /* s1 */                                                          \
    RD_SET(aX, bX, P, 2);                                                         \
    MM(aY, bY); /* s2 */                                                          \
    RD_SET(aY, bY, P, 3);                                                         \
    MM(aX, bX); /* s3 */                                                          \
    asm volatile("s_waitcnt vmcnt(0)" ::: "memory");                              \
    __builtin_amdgcn_s_barrier();                                                 \
    FENCE;                                                                        \
    if (MORE) RD_SET(aX, bX, NP, 0);                                              \
    MM(aY, bY); /* s4 */                                                          \
    FENCE;                                                                        \
    __builtin_amdgcn_s_barrier();                                                 \
    FENCE;                                                                        \
  }

__global__ __launch_bounds__(512, 2) void gemm_bin_kernel(
    const signed char* __restrict__ Xq,
    const signed char* __restrict__ Wq,
    const float* __restrict__ rscale,
    const float* __restrict__ bias,
    float* __restrict__ out) {
  // buf P: A tile [256][128B] at P*65536, B tile at P*65536+32768.
  __shared__ __align__(16) signed char smem[131072];

  const int tid = threadIdx.x;
  const int w = tid >> 6;
  const int lane = tid & 63;
  const int wm = w >> 2;      // 0..1 -> rows wm*128
  const int wn = w & 3;       // 0..3 -> cols wn*64
  const int hi = lane >> 5;   // k-half within 32-k step
  const int l31 = lane & 31;
  const size_t m0 = (size_t)blockIdx.y * BM;
  const size_t n0 = (size_t)blockIdx.x * BN;

  int16v acc[4][2];
#pragma unroll
  for (int i = 0; i < 4; ++i)
#pragma unroll
    for (int j = 0; j < 2; ++j)
#pragma unroll
      for (int r = 0; r < 16; ++r) acc[i][j][r] = 0;
  int4v aX[4], bX[2], aY[4], bY[2];  // ping-pong operand sets

  // stage one full K-tile (A 32KB + B 32KB = 8 gload_lds/thread); LDS dest
  // linear, swizzle on the global source chunk (rule 21).
  auto stage = [&](int pb, int t) {
    signed char* lb = smem + pb * 65536;
#pragma unroll
    for (int it = 0; it < 4; ++it) {
      int pos = it * 512 + tid;
      int row = pos >> 3, s = pos & 7;
      int qg = s ^ (row & 7);
      gload_lds16(Xq + (m0 + row) * (size_t)K + (size_t)t * BK + qg * 16,
                  lb + row * 128 + s * 16);
    }
#pragma unroll
    for (int it = 0; it < 4; ++it) {
      int pos = it * 512 + tid;
      int row = pos >> 3, s = pos & 7;
      int qg = s ^ (row & 7);
      gload_lds16(Wq + (n0 + row) * (size_t)K + (size_t)t * BK + qg * 16,
                  lb + 32768 + row * 128 + s * 16);
    }
  };

  // prologue: tile 0 -> buf0; tile 1 staged during tile 0.
  stage(0, 0);
  asm volatile("s_waitcnt vmcnt(0)" ::: "memory");
  __builtin_amdgcn_s_barrier();
  FENCE;
  RD_SET(aX, bX, 0, 0);

#pragma unroll 1
  for (int tt = 0; tt < NT; tt += 2) {
    TILE(0, 1, tt + 1, true)
    TILE(1, 0, tt + 2, (tt + 2 < NT))
  }

  // epilogue: 32x32 C/D layout: col=lane&31, row=(reg&3)+8*(reg>>2)+4*(lane>>5)
#pragma unroll
  for (int mi = 0; mi < 4; ++mi) {
    const size_t rbase = m0 + wm * 128 + mi * 32;
    float sc[4][4];  // [quad q][elem j]: row = rbase + hi*4 + q*8 + j
#pragma unroll
    for (int q = 0; q < 4; ++q)
      *(float4*)sc[q] = *(const float4*)(rscale + rbase + hi * 4 + q * 8);
#pragma unroll
    for (int ni = 0; ni < 2; ++ni) {
      const size_t col = n0 + wn * 64 + ni * 32 + l31;
      const float bv = bias[col];
#pragma unroll
      for (int r = 0; r < 16; ++r) {
        const int row = (r & 3) + 8 * (r >> 2) + 4 * hi;
        out[(rbase + row) * N + col] = (float)acc[mi][ni][r] * sc[r >> 2][r & 3] + bv;
      }
    }
  }
}

extern "C" void kernel_launch(void* const* d_in, const int* in_sizes, int n_in,
                              void* d_out, int out_size, void* d_ws, size_t ws_size,
                              hipStream_t stream) {
  const float* x = (const float*)d_in[0];
  const float* kern = (const float*)d_in[1];
  const float* bias = (const float*)d_in[2];
  float* out = (float*)d_out;

  signed char* Xq = (signed char*)d_ws;                 // 32 MiB
  signed char* Wq = Xq + (size_t)M * K;                 // 16 MiB
  float* rscale = (float*)(Wq + (size_t)N * K);         // 32 KiB

  prep_kernel<<<M + (N / 64) * (K / 64), 256, 0, stream>>>(x, Xq, rscale, kern, Wq);
  gemm_bin_kernel<<<dim3(N / BN, M / BM), 512, 0, stream>>>(Xq, Wq, rscale, bias, out);
}